// Round 3
// baseline (1204.666 us; speedup 1.0000x reference)
//
#include <hip/hip_runtime.h>
#include <math.h>

#define NN 100000
#define NE 1600000

__device__ __forceinline__ float relu_f(float v) { return fmaxf(v, 0.0f); }

// ---- compile-time for: guarantees every array subscript is a constant ----
template<int I> struct IC { static constexpr int v = I; };
template<int I, int N, typename F>
__device__ __forceinline__ void sfor(F&& f) {
    if constexpr (I < N) {
        f(IC<I>{});
        sfor<I + 1, N>(f);
    }
}

// out[j][k] = in[k][j], 64x64
__global__ void transpose64(const float* __restrict__ in, float* __restrict__ out) {
    int j = blockIdx.x, k = threadIdx.x;
    out[j * 64 + k] = in[k * 64 + j];
}

__global__ void init_kernel(const float* __restrict__ x, float* __restrict__ xw,
                            float* __restrict__ counts, float* __restrict__ agg) {
    int i = blockIdx.x * blockDim.x + threadIdx.x;
    if (i < NN) {
#pragma unroll
        for (int j = 0; j < 5; j++) {
            xw[i * 5 + j] = x[i * 5 + j];
            agg[i * 5 + j] = 0.0f;
        }
        counts[i] = 0.0f;
    }
}

__global__ void count_kernel(const int* __restrict__ dst, float* __restrict__ counts) {
    int e = blockIdx.x * blockDim.x + threadIdx.x;  // NE divisible by 256: no guard
    atomicAdd(&counts[dst[e]], 1.0f);
}

// EdgeModel + scatter-sum into agg. NE = 6250*256 exactly -> no guard, weight
// loads stay in uniform control flow (s_load path). All local-array indices
// are compile-time constants (sfor) so nothing can demote to scratch.
__global__ __launch_bounds__(256, 2)
void edge_kernel(const float* __restrict__ xw, const float* __restrict__ edge_attr,
                 const int* __restrict__ src_idx, const int* __restrict__ dst_idx,
                 const float* __restrict__ ew1, const float* __restrict__ eb1,
                 const float* __restrict__ ew2t, const float* __restrict__ eb2,
                 const float* __restrict__ ew3, const float* __restrict__ eb3,
                 float* __restrict__ agg) {
    int e = blockIdx.x * blockDim.x + threadIdx.x;
    int s = src_idx[e];
    int d = dst_idx[e];

    float xs[5], xd[5];
    sfor<0, 5>([&](auto J) { xs[J.v] = xw[s * 5 + J.v]; });
    sfor<0, 5>([&](auto J) { xd[J.v] = xw[d * 5 + J.v]; });

    float ea[5];
    sfor<0, 5>([&](auto J) { ea[J.v] = edge_attr[e * 5 + J.v]; });

    float ein[11];
    ein[0] = xd[0] - xs[0];
    ein[1] = xd[1] - xs[1];
    ein[2] = xd[2] - xs[2];
    ein[3] = sqrtf(ein[0] * ein[0] + ein[1] * ein[1] + ein[2] * ein[2]);
    sfor<0, 5>([&](auto J) { ein[4 + J.v] = ea[J.v]; });
    ein[9] = xs[4];
    ein[10] = xd[4];

    // layer 1: 11 -> 64, fully static
    float h1[64];
    sfor<0, 64>([&](auto J) { h1[J.v] = eb1[J.v]; });
    sfor<0, 11>([&](auto K) {
        sfor<0, 64>([&](auto J) {
            h1[J.v] = fmaf(ein[K.v], ew1[K.v * 64 + J.v], h1[J.v]);
        });
    });
    sfor<0, 64>([&](auto J) { h1[J.v] = relu_f(h1[J.v]); });

    // layer 2 (64->64) fused with layer 3 (64->5): 4 blocks of 16 outputs,
    // 16 named accumulators, immediately folded into o[5]. Weight addresses
    // depend only on the uniform kb -> scalar-load path.
    float o[5];
    sfor<0, 5>([&](auto M) { o[M.v] = eb3[M.v]; });
    for (int kb = 0; kb < 4; kb++) {
        const float* w2p = ew2t + kb * 16 * 64;
        const float* b2p = eb2 + kb * 16;
        const float* w3p = ew3 + kb * 16 * 5;
        float a[16];
        sfor<0, 16>([&](auto KK) { a[KK.v] = b2p[KK.v]; });
        sfor<0, 16>([&](auto KK) {
            sfor<0, 64>([&](auto Q) {
                a[KK.v] = fmaf(h1[Q.v], w2p[KK.v * 64 + Q.v], a[KK.v]);
            });
        });
        sfor<0, 16>([&](auto KK) {
            float r = relu_f(a[KK.v]);
            sfor<0, 5>([&](auto M) { o[M.v] = fmaf(r, w3p[KK.v * 5 + M.v], o[M.v]); });
        });
    }

    sfor<0, 5>([&](auto M) { atomicAdd(&agg[d * 5 + M.v], ea[M.v] + o[M.v]); });
}

// NodeModel: agg/count -> MLP 7->64->64->1 -> dphi; x update; re-zero agg.
__global__ __launch_bounds__(256, 2)
void node_kernel(float* __restrict__ xw, float* __restrict__ agg,
                 const float* __restrict__ counts,
                 const float* __restrict__ nw1, const float* __restrict__ nb1,
                 const float* __restrict__ nw2t, const float* __restrict__ nb2,
                 const float* __restrict__ nw3, const float* __restrict__ nb3) {
    int gid = blockIdx.x * blockDim.x + threadIdx.x;
    int i = min(gid, NN - 1);  // clamp: keep weight loads in uniform flow
    bool valid = (gid < NN);

    float cnt = fmaxf(counts[i], 1.0f);
    float nin[7];
    nin[0] = xw[i * 5 + 3];
    nin[1] = xw[i * 5 + 4];
    sfor<0, 5>([&](auto M) { nin[2 + M.v] = agg[i * 5 + M.v] / cnt; });

    float h1[64];
    sfor<0, 64>([&](auto J) { h1[J.v] = nb1[J.v]; });
    sfor<0, 7>([&](auto K) {
        sfor<0, 64>([&](auto J) {
            h1[J.v] = fmaf(nin[K.v], nw1[K.v * 64 + J.v], h1[J.v]);
        });
    });
    sfor<0, 64>([&](auto J) { h1[J.v] = relu_f(h1[J.v]); });

    // layer 2 fused with layer-3 (64->1) fold
    float dphi = nb3[0];
    for (int kb = 0; kb < 4; kb++) {
        const float* w2p = nw2t + kb * 16 * 64;
        const float* b2p = nb2 + kb * 16;
        const float* w3p = nw3 + kb * 16;
        float a[16];
        sfor<0, 16>([&](auto KK) { a[KK.v] = b2p[KK.v]; });
        sfor<0, 16>([&](auto KK) {
            sfor<0, 64>([&](auto Q) {
                a[KK.v] = fmaf(h1[Q.v], w2p[KK.v * 64 + Q.v], a[KK.v]);
            });
        });
        sfor<0, 16>([&](auto KK) { dphi = fmaf(relu_f(a[KK.v]), w3p[KK.v], dphi); });
    }

    if (valid) {
        float xv[5];
        sfor<0, 5>([&](auto M) { xv[M.v] = xw[i * 5 + M.v]; });
        xv[4] += dphi;
        sfor<0, 5>([&](auto M) {
            float t = xv[M.v];
            xw[i * 5 + M.v] = t + relu_f(t);  // x = x_mut + relu(x_mut)
            agg[i * 5 + M.v] = 0.0f;          // re-zero for next edge pass
        });
    }
}

// Decoder: 5->64->64->64->1
__global__ __launch_bounds__(256, 2)
void decoder_kernel(const float* __restrict__ xw,
                    const float* __restrict__ dw1, const float* __restrict__ db1,
                    const float* __restrict__ dw2t, const float* __restrict__ db2,
                    const float* __restrict__ dw3t, const float* __restrict__ db3,
                    const float* __restrict__ dw4, const float* __restrict__ db4,
                    float* __restrict__ out) {
    int gid = blockIdx.x * blockDim.x + threadIdx.x;
    int i = min(gid, NN - 1);
    bool valid = (gid < NN);

    float xin[5];
    sfor<0, 5>([&](auto M) { xin[M.v] = xw[i * 5 + M.v]; });

    float h1[64];
    sfor<0, 64>([&](auto J) { h1[J.v] = db1[J.v]; });
    sfor<0, 5>([&](auto K) {
        sfor<0, 64>([&](auto J) {
            h1[J.v] = fmaf(xin[K.v], dw1[K.v * 64 + J.v], h1[J.v]);
        });
    });
    sfor<0, 64>([&](auto J) { h1[J.v] = relu_f(h1[J.v]); });

    // layer 2: materialize h2[64] (static), h1 dies after
    float h2[64];
    for (int kb = 0; kb < 4; kb++) {
        const float* w2p = dw2t + kb * 16 * 64;
        const float* b2p = db2 + kb * 16;
        float a[16];
        sfor<0, 16>([&](auto KK) { a[KK.v] = b2p[KK.v]; });
        sfor<0, 16>([&](auto KK) {
            sfor<0, 64>([&](auto Q) {
                a[KK.v] = fmaf(h1[Q.v], w2p[KK.v * 64 + Q.v], a[KK.v]);
            });
        });
        switch (kb) {  // static destination indices
            case 0: sfor<0, 16>([&](auto KK) { h2[KK.v] = relu_f(a[KK.v]); }); break;
            case 1: sfor<0, 16>([&](auto KK) { h2[16 + KK.v] = relu_f(a[KK.v]); }); break;
            case 2: sfor<0, 16>([&](auto KK) { h2[32 + KK.v] = relu_f(a[KK.v]); }); break;
            case 3: sfor<0, 16>([&](auto KK) { h2[48 + KK.v] = relu_f(a[KK.v]); }); break;
        }
    }

    // layer 3 (64->64) fused with layer-4 (64->1) fold
    float o = db4[0];
    for (int jb = 0; jb < 4; jb++) {
        const float* w3p = dw3t + jb * 16 * 64;
        const float* b3p = db3 + jb * 16;
        const float* w4p = dw4 + jb * 16;
        float a[16];
        sfor<0, 16>([&](auto JJ) { a[JJ.v] = b3p[JJ.v]; });
        sfor<0, 16>([&](auto JJ) {
            sfor<0, 64>([&](auto Q) {
                a[JJ.v] = fmaf(h2[Q.v], w3p[JJ.v * 64 + Q.v], a[JJ.v]);
            });
        });
        sfor<0, 16>([&](auto JJ) { o = fmaf(relu_f(a[JJ.v]), w4p[JJ.v], o); });
    }

    if (valid) out[gid] = o;
}

extern "C" void kernel_launch(void* const* d_in, const int* in_sizes, int n_in,
                              void* d_out, int out_size, void* d_ws, size_t ws_size,
                              hipStream_t stream) {
    const float* x         = (const float*)d_in[0];
    const float* edge_attr = (const float*)d_in[1];
    const float* ew1 = (const float*)d_in[2];
    const float* eb1 = (const float*)d_in[3];
    const float* ew2 = (const float*)d_in[4];
    const float* eb2 = (const float*)d_in[5];
    const float* ew3 = (const float*)d_in[6];
    const float* eb3 = (const float*)d_in[7];
    const float* nw1 = (const float*)d_in[8];
    const float* nb1 = (const float*)d_in[9];
    const float* nw2 = (const float*)d_in[10];
    const float* nb2 = (const float*)d_in[11];
    const float* nw3 = (const float*)d_in[12];
    const float* nb3 = (const float*)d_in[13];
    const float* dw1 = (const float*)d_in[14];
    const float* db1 = (const float*)d_in[15];
    const float* dw2 = (const float*)d_in[16];
    const float* db2 = (const float*)d_in[17];
    const float* dw3 = (const float*)d_in[18];
    const float* db3 = (const float*)d_in[19];
    const float* dw4 = (const float*)d_in[20];
    const float* db4 = (const float*)d_in[21];
    const int* edge_index = (const int*)d_in[22];
    const int* src = edge_index;            // edge_index[0, :]
    const int* dst = edge_index + NE;       // edge_index[1, :]
    float* out = (float*)d_out;

    // workspace layout (floats): xw[NN*5] | counts[NN] | agg[NN*5] | 4x 64x64 transposed
    float* xw     = (float*)d_ws;
    float* counts = xw + NN * 5;
    float* agg    = counts + NN;
    float* ew2t   = agg + NN * 5;
    float* nw2t   = ew2t + 64 * 64;
    float* dw2t   = nw2t + 64 * 64;
    float* dw3t   = dw2t + 64 * 64;

    transpose64<<<64, 64, 0, stream>>>(ew2, ew2t);
    transpose64<<<64, 64, 0, stream>>>(nw2, nw2t);
    transpose64<<<64, 64, 0, stream>>>(dw2, dw2t);
    transpose64<<<64, 64, 0, stream>>>(dw3, dw3t);

    init_kernel<<<(NN + 255) / 256, 256, 0, stream>>>(x, xw, counts, agg);
    count_kernel<<<NE / 256, 256, 0, stream>>>(dst, counts);

    for (int it = 0; it < 2; it++) {
        edge_kernel<<<NE / 256, 256, 0, stream>>>(xw, edge_attr, src, dst,
                                                  ew1, eb1, ew2t, eb2, ew3, eb3, agg);
        node_kernel<<<(NN + 255) / 256, 256, 0, stream>>>(xw, agg, counts,
                                                          nw1, nb1, nw2t, nb2, nw3, nb3);
    }

    decoder_kernel<<<(NN + 255) / 256, 256, 0, stream>>>(xw, dw1, db1, dw2t, db2,
                                                         dw3t, db3, dw4, db4, out);
}

// Round 5
// 1191.453 us; speedup vs baseline: 1.0111x; 1.0111x over previous
//
#include <hip/hip_runtime.h>
#include <math.h>

#define NN 100000
#define NE 1600000

// ---------------- preprocessor repetition: NO local arrays anywhere ----------
#define R5(M,A)  M(0,A) M(1,A) M(2,A) M(3,A) M(4,A)
#define R7(M,A)  M(0,A) M(1,A) M(2,A) M(3,A) M(4,A) M(5,A) M(6,A)
#define R11(M,A) R7(M,A) M(7,A) M(8,A) M(9,A) M(10,A)
#define R16(M,A) M(0,A) M(1,A) M(2,A) M(3,A) M(4,A) M(5,A) M(6,A) M(7,A) \
                 M(8,A) M(9,A) M(10,A) M(11,A) M(12,A) M(13,A) M(14,A) M(15,A)
// inner copy: identical body, distinct name so it can nest inside R16
#define R16I(M,A) M(0,A) M(1,A) M(2,A) M(3,A) M(4,A) M(5,A) M(6,A) M(7,A) \
                  M(8,A) M(9,A) M(10,A) M(11,A) M(12,A) M(13,A) M(14,A) M(15,A)
#define R64(M,A) \
  M(0,A) M(1,A) M(2,A) M(3,A) M(4,A) M(5,A) M(6,A) M(7,A) \
  M(8,A) M(9,A) M(10,A) M(11,A) M(12,A) M(13,A) M(14,A) M(15,A) \
  M(16,A) M(17,A) M(18,A) M(19,A) M(20,A) M(21,A) M(22,A) M(23,A) \
  M(24,A) M(25,A) M(26,A) M(27,A) M(28,A) M(29,A) M(30,A) M(31,A) \
  M(32,A) M(33,A) M(34,A) M(35,A) M(36,A) M(37,A) M(38,A) M(39,A) \
  M(40,A) M(41,A) M(42,A) M(43,A) M(44,A) M(45,A) M(46,A) M(47,A) \
  M(48,A) M(49,A) M(50,A) M(51,A) M(52,A) M(53,A) M(54,A) M(55,A) \
  M(56,A) M(57,A) M(58,A) M(59,A) M(60,A) M(61,A) M(62,A) M(63,A)

// hidden layer 1 (named scalars h1_0..h1_63)
#define DECL_H1(J,P) float h1_##J = (P)[J];
#define FMA_L1(J,K)  h1_##J = fmaf(ein_##K, wrow[J], h1_##J);
#define ROW_L1(K,W)  { const float* wrow = (W) + (K)*64; R64(FMA_L1,K) }
#define RELU_H1(J,A) h1_##J = fmaxf(h1_##J, 0.0f);

// 16-wide accumulator block (named scalars a_0..a_15)
#define DECL_A(K,P)  float a_##K = (P)[K];
#define FMA_L2(Q,K)  a_##K = fmaf(h1_##Q, w2p[(K)*64+Q], a_##K);
#define ROW_L2(K,A)  R64(FMA_L2,K)

// edge layer-3 fold (64->5)
#define FOLD_E(K,A) { float r = fmaxf(a_##K, 0.0f); \
  o_0 = fmaf(r, w3p[(K)*5+0], o_0); o_1 = fmaf(r, w3p[(K)*5+1], o_1); \
  o_2 = fmaf(r, w3p[(K)*5+2], o_2); o_3 = fmaf(r, w3p[(K)*5+3], o_3); \
  o_4 = fmaf(r, w3p[(K)*5+4], o_4); }

// node layer-3 fold (64->1)
#define FOLD_N(K,A)  dphi = fmaf(fmaxf(a_##K, 0.0f), w3p[K], dphi);

// decoder h2 (four named groups of 16)
#define DECL_H2(K,G) float h2##G##_##K;
#define ASG_H2(K,G)  h2##G##_##K = fmaxf(a_##K, 0.0f);
#define L2BLK(G,B)   { const float* w2p = dw2t + (B)*1024; const float* b2p = db2 + (B)*16; \
                       R16(DECL_A,b2p) R16(ROW_L2,0) R16(ASG_H2,G) }
#define FMA_L3A(Q,K) a_##K = fmaf(h2A_##Q, w3p[(K)*64+Q],    a_##K);
#define FMA_L3B(Q,K) a_##K = fmaf(h2B_##Q, w3p[(K)*64+16+Q], a_##K);
#define FMA_L3C(Q,K) a_##K = fmaf(h2C_##Q, w3p[(K)*64+32+Q], a_##K);
#define FMA_L3D(Q,K) a_##K = fmaf(h2D_##Q, w3p[(K)*64+48+Q], a_##K);
#define ROW_L3(K,A)  R16I(FMA_L3A,K) R16I(FMA_L3B,K) R16I(FMA_L3C,K) R16I(FMA_L3D,K)
#define FOLD_D(K,A)  o = fmaf(fmaxf(a_##K, 0.0f), w4p[K], o);

// out[j][k] = in[k][j], 64x64
__global__ void transpose64(const float* __restrict__ in, float* __restrict__ out) {
    int j = blockIdx.x, k = threadIdx.x;
    out[j * 64 + k] = in[k * 64 + j];
}

__global__ void init_kernel(const float* __restrict__ x, float* __restrict__ xw,
                            float* __restrict__ counts, float* __restrict__ agg) {
    int i = blockIdx.x * blockDim.x + threadIdx.x;
    if (i < NN) {
#pragma unroll
        for (int j = 0; j < 5; j++) {
            xw[i * 5 + j] = x[i * 5 + j];
            agg[i * 5 + j] = 0.0f;
        }
        counts[i] = 0.0f;
    }
}

__global__ void count_kernel(const int* __restrict__ dst, float* __restrict__ counts) {
    int e = blockIdx.x * blockDim.x + threadIdx.x;  // NE divisible by 256: no guard
    atomicAdd(&counts[dst[e]], 1.0f);
}

// EdgeModel + scatter-sum into agg. NE = 6250*256 -> no guard; weight loads
// uniform (s_load path); ALL intermediates are named scalars (no allocas).
__global__ __launch_bounds__(256, 2)
void edge_kernel(const float* __restrict__ xw, const float* __restrict__ edge_attr,
                 const int* __restrict__ src_idx, const int* __restrict__ dst_idx,
                 const float* __restrict__ ew1, const float* __restrict__ eb1,
                 const float* __restrict__ ew2t, const float* __restrict__ eb2,
                 const float* __restrict__ ew3, const float* __restrict__ eb3,
                 float* __restrict__ agg) {
    int e = blockIdx.x * blockDim.x + threadIdx.x;
    int s = src_idx[e];
    int d = dst_idx[e];

    float xs_0 = xw[s*5+0], xs_1 = xw[s*5+1], xs_2 = xw[s*5+2], xs_4 = xw[s*5+4];
    float xd_0 = xw[d*5+0], xd_1 = xw[d*5+1], xd_2 = xw[d*5+2], xd_4 = xw[d*5+4];
    float ea_0 = edge_attr[e*5+0], ea_1 = edge_attr[e*5+1], ea_2 = edge_attr[e*5+2],
          ea_3 = edge_attr[e*5+3], ea_4 = edge_attr[e*5+4];

    float ein_0 = xd_0 - xs_0;
    float ein_1 = xd_1 - xs_1;
    float ein_2 = xd_2 - xs_2;
    float ein_3 = sqrtf(ein_0*ein_0 + ein_1*ein_1 + ein_2*ein_2);
    float ein_4 = ea_0, ein_5 = ea_1, ein_6 = ea_2, ein_7 = ea_3, ein_8 = ea_4;
    float ein_9 = xs_4, ein_10 = xd_4;

    // layer 1: 11 -> 64
    R64(DECL_H1, eb1)
    R11(ROW_L1, ew1)
    R64(RELU_H1, 0)

    // layer 2 (64->64) fused with layer 3 (64->5), 4 uniform kb blocks
    float o_0 = eb3[0], o_1 = eb3[1], o_2 = eb3[2], o_3 = eb3[3], o_4 = eb3[4];
    for (int kb = 0; kb < 4; kb++) {
        const float* w2p = ew2t + kb * 1024;
        const float* b2p = eb2 + kb * 16;
        const float* w3p = ew3 + kb * 80;
        R16(DECL_A, b2p)
        R16(ROW_L2, 0)
        R16(FOLD_E, 0)
    }

    atomicAdd(&agg[d*5+0], ea_0 + o_0);
    atomicAdd(&agg[d*5+1], ea_1 + o_1);
    atomicAdd(&agg[d*5+2], ea_2 + o_2);
    atomicAdd(&agg[d*5+3], ea_3 + o_3);
    atomicAdd(&agg[d*5+4], ea_4 + o_4);
}

// NodeModel: agg/count -> MLP 7->64->64->1 -> dphi; x update; re-zero agg.
__global__ __launch_bounds__(256, 2)
void node_kernel(float* __restrict__ xw, float* __restrict__ agg,
                 const float* __restrict__ counts,
                 const float* __restrict__ nw1, const float* __restrict__ nb1,
                 const float* __restrict__ nw2t, const float* __restrict__ nb2,
                 const float* __restrict__ nw3, const float* __restrict__ nb3) {
    int gid = blockIdx.x * blockDim.x + threadIdx.x;
    int i = min(gid, NN - 1);  // clamp: keep weight loads in uniform flow
    bool valid = (gid < NN);

    float cnt = fmaxf(counts[i], 1.0f);
    float ein_0 = xw[i*5+3];
    float ein_1 = xw[i*5+4];
    float ein_2 = agg[i*5+0] / cnt;
    float ein_3 = agg[i*5+1] / cnt;
    float ein_4 = agg[i*5+2] / cnt;
    float ein_5 = agg[i*5+3] / cnt;
    float ein_6 = agg[i*5+4] / cnt;

    R64(DECL_H1, nb1)
    R7(ROW_L1, nw1)
    R64(RELU_H1, 0)

    float dphi = nb3[0];
    for (int kb = 0; kb < 4; kb++) {
        const float* w2p = nw2t + kb * 1024;
        const float* b2p = nb2 + kb * 16;
        const float* w3p = nw3 + kb * 16;
        R16(DECL_A, b2p)
        R16(ROW_L2, 0)
        R16(FOLD_N, 0)
    }

    if (valid) {
        float x0 = xw[i*5+0], x1 = xw[i*5+1], x2 = xw[i*5+2], x3 = xw[i*5+3], x4 = xw[i*5+4];
        x4 += dphi;
        xw[i*5+0] = x0 + fmaxf(x0, 0.0f);
        xw[i*5+1] = x1 + fmaxf(x1, 0.0f);
        xw[i*5+2] = x2 + fmaxf(x2, 0.0f);
        xw[i*5+3] = x3 + fmaxf(x3, 0.0f);
        xw[i*5+4] = x4 + fmaxf(x4, 0.0f);
        agg[i*5+0] = 0.0f; agg[i*5+1] = 0.0f; agg[i*5+2] = 0.0f;
        agg[i*5+3] = 0.0f; agg[i*5+4] = 0.0f;
    }
}

// Decoder: 5->64->64->64->1
__global__ __launch_bounds__(256, 2)
void decoder_kernel(const float* __restrict__ xw,
                    const float* __restrict__ dw1, const float* __restrict__ db1,
                    const float* __restrict__ dw2t, const float* __restrict__ db2,
                    const float* __restrict__ dw3t, const float* __restrict__ db3,
                    const float* __restrict__ dw4, const float* __restrict__ db4,
                    float* __restrict__ out) {
    int gid = blockIdx.x * blockDim.x + threadIdx.x;
    int i = min(gid, NN - 1);
    bool valid = (gid < NN);

    float ein_0 = xw[i*5+0], ein_1 = xw[i*5+1], ein_2 = xw[i*5+2],
          ein_3 = xw[i*5+3], ein_4 = xw[i*5+4];

    R64(DECL_H1, db1)
    R5(ROW_L1, dw1)
    R64(RELU_H1, 0)

    // layer 2: h1 -> h2 (four named groups of 16), fully unrolled blocks
    R16(DECL_H2, A) R16(DECL_H2, B) R16(DECL_H2, C) R16(DECL_H2, D)
    L2BLK(A, 0) L2BLK(B, 1) L2BLK(C, 2) L2BLK(D, 3)

    // layer 3 (64->64) fused with layer-4 (64->1) fold, uniform jb blocks
    float o = db4[0];
    for (int jb = 0; jb < 4; jb++) {
        const float* w3p = dw3t + jb * 1024;
        const float* b3p = db3 + jb * 16;
        const float* w4p = dw4 + jb * 16;
        R16(DECL_A, b3p)
        R16(ROW_L3, 0)
        R16(FOLD_D, 0)
    }

    if (valid) out[gid] = o;
}

extern "C" void kernel_launch(void* const* d_in, const int* in_sizes, int n_in,
                              void* d_out, int out_size, void* d_ws, size_t ws_size,
                              hipStream_t stream) {
    const float* x         = (const float*)d_in[0];
    const float* edge_attr = (const float*)d_in[1];
    const float* ew1 = (const float*)d_in[2];
    const float* eb1 = (const float*)d_in[3];
    const float* ew2 = (const float*)d_in[4];
    const float* eb2 = (const float*)d_in[5];
    const float* ew3 = (const float*)d_in[6];
    const float* eb3 = (const float*)d_in[7];
    const float* nw1 = (const float*)d_in[8];
    const float* nb1 = (const float*)d_in[9];
    const float* nw2 = (const float*)d_in[10];
    const float* nb2 = (const float*)d_in[11];
    const float* nw3 = (const float*)d_in[12];
    const float* nb3 = (const float*)d_in[13];
    const float* dw1 = (const float*)d_in[14];
    const float* db1 = (const float*)d_in[15];
    const float* dw2 = (const float*)d_in[16];
    const float* db2 = (const float*)d_in[17];
    const float* dw3 = (const float*)d_in[18];
    const float* db3 = (const float*)d_in[19];
    const float* dw4 = (const float*)d_in[20];
    const float* db4 = (const float*)d_in[21];
    const int* edge_index = (const int*)d_in[22];
    const int* src = edge_index;            // edge_index[0, :]
    const int* dst = edge_index + NE;       // edge_index[1, :]
    float* out = (float*)d_out;

    // workspace layout (floats): xw[NN*5] | counts[NN] | agg[NN*5] | 4x 64x64 transposed
    float* xw     = (float*)d_ws;
    float* counts = xw + NN * 5;
    float* agg    = counts + NN;
    float* ew2t   = agg + NN * 5;
    float* nw2t   = ew2t + 64 * 64;
    float* dw2t   = nw2t + 64 * 64;
    float* dw3t   = dw2t + 64 * 64;

    transpose64<<<64, 64, 0, stream>>>(ew2, ew2t);
    transpose64<<<64, 64, 0, stream>>>(nw2, nw2t);
    transpose64<<<64, 64, 0, stream>>>(dw2, dw2t);
    transpose64<<<64, 64, 0, stream>>>(dw3, dw3t);

    init_kernel<<<(NN + 255) / 256, 256, 0, stream>>>(x, xw, counts, agg);
    count_kernel<<<NE / 256, 256, 0, stream>>>(dst, counts);

    for (int it = 0; it < 2; it++) {
        edge_kernel<<<NE / 256, 256, 0, stream>>>(xw, edge_attr, src, dst,
                                                  ew1, eb1, ew2t, eb2, ew3, eb3, agg);
        node_kernel<<<(NN + 255) / 256, 256, 0, stream>>>(xw, agg, counts,
                                                          nw1, nb1, nw2t, nb2, nw3, nb3);
    }

    decoder_kernel<<<(NN + 255) / 256, 256, 0, stream>>>(xw, dw1, db1, dw2t, db2,
                                                         dw3t, db3, dw4, db4, out);
}